// Round 3
// baseline (133.104 us; speedup 1.0000x reference)
//
#include <hip/hip_runtime.h>
#include <math.h>

#define D 256
#define CLS 10
#define BLOCK 256
#define NWAVE 4            // 256 threads / 64 lanes
#define PSTRIDE 516        // 512 class-sum floats + cnt8 + cnt9 + intra (+1 pad)
#define MAIN_BLOCKS 2048
#define RED_BLOCKS 64

// v += dpp_move(v, ctrl); invalid source lanes contribute 0 (bound_ctrl=1).
__device__ __forceinline__ float dpp_add(float v, const int ctrl) {
    int moved;
    switch (ctrl) {
        case 0x111: moved = __builtin_amdgcn_update_dpp(0, __float_as_int(v), 0x111, 0xf, 0xf, true); break;
        case 0x112: moved = __builtin_amdgcn_update_dpp(0, __float_as_int(v), 0x112, 0xf, 0xf, true); break;
        case 0x114: moved = __builtin_amdgcn_update_dpp(0, __float_as_int(v), 0x114, 0xf, 0xf, true); break;
        case 0x118: moved = __builtin_amdgcn_update_dpp(0, __float_as_int(v), 0x118, 0xf, 0xf, true); break;
        case 0x142: moved = __builtin_amdgcn_update_dpp(0, __float_as_int(v), 0x142, 0xf, 0xf, true); break;
        default:    moved = __builtin_amdgcn_update_dpp(0, __float_as_int(v), 0x143, 0xf, 0xf, true); break;
    }
    return v + __int_as_float(moved);
}

// Full 64-lane sum; result valid in lane 63. 6 VALU ops, 0 DS ops.
// All lanes hold nonneg partial sums when inputs are nonneg (bound_ctrl zeros).
__device__ __forceinline__ float wave_sum63(float v) {
    v = dpp_add(v, 0x111);
    v = dpp_add(v, 0x112);
    v = dpp_add(v, 0x114);
    v = dpp_add(v, 0x118);
    v = dpp_add(v, 0x142);
    v = dpp_add(v, 0x143);
    return v;
}

__device__ __forceinline__ float fast_sqrt(float x) {
    float r;
    asm("v_sqrt_f32 %0, %1" : "=v"(r) : "v"(x));  // ~1 ulp, 1 instr (vs sqrtf's fixup seq)
    return r;
}

// ---------------- Kernel 1: streaming pass over features ----------------
__global__ __launch_bounds__(BLOCK) void loss_main(
    const float* __restrict__ feat, const int* __restrict__ labels,
    const float* __restrict__ center, float* __restrict__ partials,
    int nrows, int nblocks)
{
    __shared__ __align__(16) float s_center[CLS * D];   // 10 KiB
    __shared__ float s_acc[NWAVE][2 * D];               // 8 KiB
    __shared__ float s_scal[NWAVE][3];

    for (int i = threadIdx.x; i < CLS * D; i += BLOCK) s_center[i] = center[i];
    __syncthreads();

    const int wave = threadIdx.x >> 6;
    const int lane = threadIdx.x & 63;
    const int gw = blockIdx.x * NWAVE + wave;
    const int nw = nblocks * NWAVE;
    const int npair = nrows >> 1;
    const int loff = lane << 2;          // float offset within a row

    float intra = 0.f, cnt8 = 0.f, cnt9 = 0.f;
    float a8x = 0.f, a8y = 0.f, a8z = 0.f, a8w = 0.f;
    float a9x = 0.f, a9y = 0.f, a9z = 0.f, a9w = 0.f;

    // processes rows 2p (fa) and 2p+1 (fb); labels wave-uniform -> scalar branches
    auto process_pair = [&](int2 lp, float4 fa, float4 fb) {
        const int sl0 = __builtin_amdgcn_readfirstlane(lp.x);
        const int sl1 = __builtin_amdgcn_readfirstlane(lp.y);
        const float4 c0 = *(const float4*)(s_center + sl0 * D + loff);
        const float4 c1 = *(const float4*)(s_center + sl1 * D + loff);

        float tx = fa.x - c0.x, ty = fa.y - c0.y, tz = fa.z - c0.z, tw = fa.w - c0.w;
        float v0 = tx * tx;
        v0 = fmaf(ty, ty, v0); v0 = fmaf(tz, tz, v0); v0 = fmaf(tw, tw, v0);
        float ux = fb.x - c1.x, uy = fb.y - c1.y, uz = fb.z - c1.z, uw = fb.w - c1.w;
        float v1 = ux * ux;
        v1 = fmaf(uy, uy, v1); v1 = fmaf(uz, uz, v1); v1 = fmaf(uw, uw, v1);

        const float s0 = wave_sum63(v0);    // two independent DPP chains -> ILP
        const float s1 = wave_sum63(v1);
        // all-lane: only lane 63 is the true row sum; others are bounded garbage,
        // discarded at store time. 1-instr sqrt keeps the all-lane cost tiny.
        intra += fminf(fmaxf(fast_sqrt(s0), 1e-16f), 1e16f);
        intra += fminf(fmaxf(fast_sqrt(s1), 1e-16f), 1e16f);

        if (sl0 == CLS - 2)      { a8x += fa.x; a8y += fa.y; a8z += fa.z; a8w += fa.w; cnt8 += 1.f; }
        else if (sl0 == CLS - 1) { a9x += fa.x; a9y += fa.y; a9z += fa.z; a9w += fa.w; cnt9 += 1.f; }
        if (sl1 == CLS - 2)      { a8x += fb.x; a8y += fb.y; a8z += fb.z; a8w += fb.w; cnt8 += 1.f; }
        else if (sl1 == CLS - 1) { a9x += fb.x; a9y += fb.y; a9z += fb.z; a9w += fb.w; cnt9 += 1.f; }
    };

    // prefetch-split loop: inner body has NO conditionals (last iter peeled)
    int p = gw;
    const bool any = p < npair;
    int2 lp = make_int2(0, 0);
    float4 f0 = make_float4(0.f, 0.f, 0.f, 0.f), f1 = f0;
    if (any) {
        lp = *(const int2*)(labels + 2 * (size_t)p);
        const float* b = feat + 2 * (size_t)p * D + loff;
        f0 = *(const float4*)(b);
        f1 = *(const float4*)(b + D);
    }
    int pn = p + nw;
    while (pn < npair) {
        const int2 lpn = *(const int2*)(labels + 2 * (size_t)pn);
        const float* bn = feat + 2 * (size_t)pn * D + loff;
        const float4 f0n = *(const float4*)(bn);
        const float4 f1n = *(const float4*)(bn + D);

        process_pair(lp, f0, f1);

        lp = lpn; f0 = f0n; f1 = f1n; pn += nw;
    }
    if (any) process_pair(lp, f0, f1);

    // odd trailing row (generic; not hit at B=262144)
    if ((nrows & 1) && gw == 0) {
        const int rl = nrows - 1;
        const int sl = __builtin_amdgcn_readfirstlane(labels[rl]);
        const float4 f = *(const float4*)(feat + (size_t)rl * D + loff);
        const float4 c = *(const float4*)(s_center + sl * D + loff);
        float tx = f.x - c.x, ty = f.y - c.y, tz = f.z - c.z, tw = f.w - c.w;
        float v = tx * tx;
        v = fmaf(ty, ty, v); v = fmaf(tz, tz, v); v = fmaf(tw, tw, v);
        const float s = wave_sum63(v);
        intra += fminf(fmaxf(fast_sqrt(s), 1e-16f), 1e16f);
        if (sl == CLS - 2)      { a8x += f.x; a8y += f.y; a8z += f.z; a8w += f.w; cnt8 += 1.f; }
        else if (sl == CLS - 1) { a9x += f.x; a9y += f.y; a9z += f.z; a9w += f.w; cnt9 += 1.f; }
    }

    const int e = loff;
    s_acc[wave][e + 0] = a8x;  s_acc[wave][e + 1] = a8y;
    s_acc[wave][e + 2] = a8z;  s_acc[wave][e + 3] = a8w;
    s_acc[wave][D + e + 0] = a9x;  s_acc[wave][D + e + 1] = a9y;
    s_acc[wave][D + e + 2] = a9z;  s_acc[wave][D + e + 3] = a9w;
    if (lane == 63) {
        s_scal[wave][0] = cnt8;
        s_scal[wave][1] = cnt9;
        s_scal[wave][2] = intra;   // lane 63 holds the true accumulated sums
    }
    __syncthreads();

    float* po = partials + (size_t)blockIdx.x * PSTRIDE;
    for (int i = threadIdx.x; i < 2 * D; i += BLOCK)
        po[i] = s_acc[0][i] + s_acc[1][i] + s_acc[2][i] + s_acc[3][i];
    if (threadIdx.x < 3)
        po[2 * D + threadIdx.x] = s_scal[0][threadIdx.x] + s_scal[1][threadIdx.x]
                                + s_scal[2][threadIdx.x] + s_scal[3][threadIdx.x];
}

// ---------------- Kernel 2: deterministic tree reduce of block partials ----------------
__global__ __launch_bounds__(BLOCK) void loss_reduce(
    const float* __restrict__ partials, float* __restrict__ out2, int nblocks)
{
    const int t = threadIdx.x;
    float s0 = 0.f, s1 = 0.f, sc = 0.f;
    for (int r = blockIdx.x; r < nblocks; r += gridDim.x) {
        const float* p = partials + (size_t)r * PSTRIDE;
        s0 += p[t];
        s1 += p[D + t];
        if (t < 3) sc += p[2 * D + t];
    }
    float* o = out2 + (size_t)blockIdx.x * PSTRIDE;
    o[t] = s0;
    o[D + t] = s1;
    if (t < 3) o[2 * D + t] = sc;
}

// ---------------- Kernel 3: final combine (fp64) + center copy ----------------
__global__ __launch_bounds__(BLOCK) void loss_final(
    const float* __restrict__ partials2, const float* __restrict__ center,
    float* __restrict__ out, int nred, int nrows)
{
    const int t = threadIdx.x;
    double s8 = 0.0, s9 = 0.0;
    for (int r = 0; r < nred; ++r) {
        const float* p = partials2 + (size_t)r * PSTRIDE;
        s8 += (double)p[t];
        s9 += (double)p[D + t];
    }
    __shared__ double sh[3];
    if (t < 3) {
        double s = 0.0;
        for (int r = 0; r < nred; ++r)
            s += (double)partials2[(size_t)r * PSTRIDE + 2 * D + t];
        sh[t] = s;
    }
    __shared__ double ssq[BLOCK];
    __syncthreads();

    const double cnt8 = fmax(sh[0], 1.0);
    const double cnt9 = fmax(sh[1], 1.0);
    const double c8 = ((double)center[(CLS - 2) * D + t] + s8) / cnt8;
    const double c9 = ((double)center[(CLS - 1) * D + t] + s9) / cnt9;
    const double diff = c8 - c9;
    ssq[t] = diff * diff;
    __syncthreads();

    for (int s = BLOCK / 2; s > 0; s >>= 1) {
        if (t < s) ssq[t] += ssq[t + s];
        __syncthreads();
    }

    if (t == 0) {
        const double last = sqrt(fmax(ssq[0], 0.0));
        const double denom = fmin(fmax(2.0 * last, 1e-16), 1e16);
        out[0] = (float)(sh[2] / (double)nrows);
        out[1] = (float)(1.0 / denom);
    }
    for (int i = t; i < CLS * D; i += BLOCK) out[2 + i] = center[i];
}

extern "C" void kernel_launch(void* const* d_in, const int* in_sizes, int n_in,
                              void* d_out, int out_size, void* d_ws, size_t ws_size,
                              hipStream_t stream) {
    const float* feat   = (const float*)d_in[0];
    const int*   labels = (const int*)d_in[1];
    const float* center = (const float*)d_in[2];
    float* out = (float*)d_out;

    const int nrows = in_sizes[0] / D;

    int nblocks = MAIN_BLOCKS;
    while (nblocks > 64 &&
           ((size_t)nblocks + RED_BLOCKS) * PSTRIDE * sizeof(float) > ws_size)
        nblocks >>= 1;

    float* partials  = (float*)d_ws;
    float* partials2 = partials + (size_t)nblocks * PSTRIDE;

    loss_main<<<nblocks, BLOCK, 0, stream>>>(feat, labels, center, partials, nrows, nblocks);
    loss_reduce<<<RED_BLOCKS, BLOCK, 0, stream>>>(partials, partials2, nblocks);
    loss_final<<<1, BLOCK, 0, stream>>>(partials2, center, out, RED_BLOCKS, nrows);
}

// Round 4
// 130.745 us; speedup vs baseline: 1.0180x; 1.0180x over previous
//
#include <hip/hip_runtime.h>
#include <math.h>

#define D 256
#define CLS 10
#define BLOCK 256
#define NWAVE 4            // 256 threads / 64 lanes
#define PSTRIDE 516        // 512 class-sum floats + cnt8 + cnt9 + intra (+1 pad)
#define MAIN_BLOCKS 2048
#define RED_BLOCKS 64

typedef float f32x4 __attribute__((ext_vector_type(4)));

__device__ __forceinline__ f32x4 ntload4(const float* p) {
    return __builtin_nontemporal_load((const f32x4*)p);
}

// v += dpp_move(v, ctrl); invalid source lanes contribute 0 (bound_ctrl=1).
__device__ __forceinline__ float dpp_add(float v, const int ctrl) {
    int moved;
    switch (ctrl) {
        case 0x111: moved = __builtin_amdgcn_update_dpp(0, __float_as_int(v), 0x111, 0xf, 0xf, true); break;
        case 0x112: moved = __builtin_amdgcn_update_dpp(0, __float_as_int(v), 0x112, 0xf, 0xf, true); break;
        case 0x114: moved = __builtin_amdgcn_update_dpp(0, __float_as_int(v), 0x114, 0xf, 0xf, true); break;
        case 0x118: moved = __builtin_amdgcn_update_dpp(0, __float_as_int(v), 0x118, 0xf, 0xf, true); break;
        case 0x142: moved = __builtin_amdgcn_update_dpp(0, __float_as_int(v), 0x142, 0xf, 0xf, true); break;
        default:    moved = __builtin_amdgcn_update_dpp(0, __float_as_int(v), 0x143, 0xf, 0xf, true); break;
    }
    return v + __int_as_float(moved);
}

// Full 64-lane sum; result valid in lane 63. 6 VALU ops, 0 DS ops.
__device__ __forceinline__ float wave_sum63(float v) {
    v = dpp_add(v, 0x111);
    v = dpp_add(v, 0x112);
    v = dpp_add(v, 0x114);
    v = dpp_add(v, 0x118);
    v = dpp_add(v, 0x142);
    v = dpp_add(v, 0x143);
    return v;
}

__device__ __forceinline__ float fast_sqrt(float x) {
    float r;
    asm("v_sqrt_f32 %0, %1" : "=v"(r) : "v"(x));  // ~1 ulp, single instr
    return r;
}

// ---------------- Kernel 1: streaming pass over features ----------------
__global__ __launch_bounds__(BLOCK) void loss_main(
    const float* __restrict__ feat, const int* __restrict__ labels,
    const float* __restrict__ center, float* __restrict__ partials,
    int nrows, int nblocks)
{
    __shared__ __align__(16) float s_center[CLS * D];   // 10 KiB
    __shared__ float s_acc[NWAVE][2 * D];               // 8 KiB
    __shared__ float s_scal[NWAVE][3];

    for (int i = threadIdx.x; i < CLS * D; i += BLOCK) s_center[i] = center[i];
    __syncthreads();

    const int wave = threadIdx.x >> 6;
    const int lane = threadIdx.x & 63;
    const int gw = blockIdx.x * NWAVE + wave;
    const int nw = nblocks * NWAVE;
    const int loff = lane << 2;

    float intra = 0.f, cnt8 = 0.f, cnt9 = 0.f;
    float a8x = 0.f, a8y = 0.f, a8z = 0.f, a8w = 0.f;
    float a9x = 0.f, a9y = 0.f, a9z = 0.f, a9w = 0.f;

    // identical body to the 89us round-2 version (vector compares, lane-63
    // epilogue), direct ||f-c||^2
    auto process = [&](int l, f32x4 f) {
        const float4 c = *(const float4*)(s_center + l * D + loff);
        float tx = f.x - c.x, ty = f.y - c.y, tz = f.z - c.z, tw = f.w - c.w;
        float v = tx * tx;
        v = fmaf(ty, ty, v); v = fmaf(tz, tz, v); v = fmaf(tw, tw, v);
        const float s = wave_sum63(v);
        if (lane == 63) {
            intra += fminf(fmaxf(fast_sqrt(fmaxf(s, 0.f)), 1e-16f), 1e16f);
            cnt8 += (l == CLS - 2) ? 1.f : 0.f;
            cnt9 += (l == CLS - 1) ? 1.f : 0.f;
        }
        if (l == CLS - 2) { a8x += f.x; a8y += f.y; a8z += f.z; a8w += f.w; }
        if (l == CLS - 1) { a9x += f.x; a9y += f.y; a9z += f.z; a9w += f.w; }
    };

    // depth-2 prefetch: 2 KiB/wave in flight, steady-state body unconditional
    int r = gw;
    int l0 = 0, l1 = 0;
    f32x4 f0 = (f32x4)0.f, f1 = (f32x4)0.f;
    const bool v0 = r < nrows;
    const bool v1 = r + nw < nrows;
    if (v0) { l0 = labels[r];      f0 = ntload4(feat + (size_t)r * D + loff); }
    if (v1) { l1 = labels[r + nw]; f1 = ntload4(feat + ((size_t)r + nw) * D + loff); }

    while (r + 2 * nw < nrows) {
        const int l2 = labels[r + 2 * nw];
        const f32x4 f2 = ntload4(feat + ((size_t)r + 2 * nw) * D + loff);
        process(l0, f0);
        l0 = l1; f0 = f1; l1 = l2; f1 = f2;
        r += nw;
    }
    if (v0) process(l0, f0);
    if (v1) process(l1, f1);

    const int e = loff;
    s_acc[wave][e + 0] = a8x;  s_acc[wave][e + 1] = a8y;
    s_acc[wave][e + 2] = a8z;  s_acc[wave][e + 3] = a8w;
    s_acc[wave][D + e + 0] = a9x;  s_acc[wave][D + e + 1] = a9y;
    s_acc[wave][D + e + 2] = a9z;  s_acc[wave][D + e + 3] = a9w;
    if (lane == 63) {
        s_scal[wave][0] = cnt8;
        s_scal[wave][1] = cnt9;
        s_scal[wave][2] = intra;
    }
    __syncthreads();

    float* po = partials + (size_t)blockIdx.x * PSTRIDE;
    for (int i = threadIdx.x; i < 2 * D; i += BLOCK)
        po[i] = s_acc[0][i] + s_acc[1][i] + s_acc[2][i] + s_acc[3][i];
    if (threadIdx.x < 3)
        po[2 * D + threadIdx.x] = s_scal[0][threadIdx.x] + s_scal[1][threadIdx.x]
                                + s_scal[2][threadIdx.x] + s_scal[3][threadIdx.x];
}

// ------- Kernel 2 (fused): tree reduce + last-block final combine -------
__global__ __launch_bounds__(BLOCK) void loss_tail(
    const float* __restrict__ partials, float* __restrict__ partials2,
    const float* __restrict__ center, float* __restrict__ out,
    unsigned* __restrict__ counter, int nblocks, int nrows)
{
    const int t = threadIdx.x;
    __shared__ bool is_last;

    // ---- stage 1: this block reduces its strided slice of partials ----
    float s0 = 0.f, s1 = 0.f, sc = 0.f;
    for (int r = blockIdx.x; r < nblocks; r += gridDim.x) {
        const float* p = partials + (size_t)r * PSTRIDE;
        s0 += p[t];
        s1 += p[D + t];
        if (t < 3) sc += p[2 * D + t];
    }
    float* o = partials2 + (size_t)blockIdx.x * PSTRIDE;
    o[t] = s0;
    o[D + t] = s1;
    if (t < 3) o[2 * D + t] = sc;

    // center passthrough (independent work, done in parallel by block 0)
    if (blockIdx.x == 0)
        for (int i = t; i < CLS * D; i += BLOCK) out[2 + i] = center[i];

    // ---- release: make stores device-visible, then count this block done ----
    __threadfence();
    __syncthreads();
    if (t == 0) {
        const unsigned old = atomicAdd(counter, 1u);
        is_last = (old == gridDim.x - 1);
    }
    __syncthreads();
    if (!is_last) return;
    __threadfence();  // acquire: see all other blocks' partials2 stores

    // ---- final combine (one block, fixed read order -> bit-deterministic) ----
    const int nred = gridDim.x;
    double s8 = 0.0, s9 = 0.0;
    for (int r = 0; r < nred; ++r) {
        const float* p = partials2 + (size_t)r * PSTRIDE;
        s8 += (double)p[t];
        s9 += (double)p[D + t];
    }
    __shared__ double sh[3];
    if (t < 3) {
        double s = 0.0;
        for (int r = 0; r < nred; ++r)
            s += (double)partials2[(size_t)r * PSTRIDE + 2 * D + t];
        sh[t] = s;
    }
    __shared__ double ssq[BLOCK];
    __syncthreads();

    const double cnt8 = fmax(sh[0], 1.0);
    const double cnt9 = fmax(sh[1], 1.0);
    const double c8 = ((double)center[(CLS - 2) * D + t] + s8) / cnt8;
    const double c9 = ((double)center[(CLS - 1) * D + t] + s9) / cnt9;
    const double diff = c8 - c9;
    ssq[t] = diff * diff;
    __syncthreads();

    for (int s = BLOCK / 2; s > 0; s >>= 1) {
        if (t < s) ssq[t] += ssq[t + s];
        __syncthreads();
    }

    if (t == 0) {
        const double last = sqrt(fmax(ssq[0], 0.0));
        const double denom = fmin(fmax(2.0 * last, 1e-16), 1e16);
        out[0] = (float)(sh[2] / (double)nrows);
        out[1] = (float)(1.0 / denom);
    }
}

extern "C" void kernel_launch(void* const* d_in, const int* in_sizes, int n_in,
                              void* d_out, int out_size, void* d_ws, size_t ws_size,
                              hipStream_t stream) {
    const float* feat   = (const float*)d_in[0];
    const int*   labels = (const int*)d_in[1];
    const float* center = (const float*)d_in[2];
    float* out = (float*)d_out;

    const int nrows = in_sizes[0] / D;

    int nblocks = MAIN_BLOCKS;
    while (nblocks > 64 &&
           ((size_t)nblocks + RED_BLOCKS + 1) * PSTRIDE * sizeof(float) > ws_size)
        nblocks >>= 1;

    float* partials  = (float*)d_ws;
    float* partials2 = partials + (size_t)nblocks * PSTRIDE;
    unsigned* counter = (unsigned*)(partials2 + (size_t)RED_BLOCKS * PSTRIDE);

    // zero the done-counter every call (ws is poisoned once, never re-poisoned)
    hipMemsetAsync(counter, 0, sizeof(unsigned), stream);

    loss_main<<<nblocks, BLOCK, 0, stream>>>(feat, labels, center, partials, nrows, nblocks);
    loss_tail<<<RED_BLOCKS, BLOCK, 0, stream>>>(partials, partials2, center, out,
                                                counter, nblocks, nrows);
}

// Round 5
// 96.264 us; speedup vs baseline: 1.3827x; 1.3582x over previous
//
#include <hip/hip_runtime.h>
#include <math.h>

#define D 256
#define CLS 10
#define BLOCK 256
#define NWAVE 4            // 256 threads / 64 lanes
#define PSTRIDE 516        // 512 class-sum floats + cnt8 + cnt9 + intra (+1 pad)
#define MAIN_BLOCKS 2048
#define RED_BLOCKS 64

// v += dpp_move(v, ctrl); invalid source lanes contribute 0 (bound_ctrl=1).
// Pure VALU — no LDS pipe traffic, unlike __shfl_xor (ds_bpermute).
__device__ __forceinline__ float dpp_add(float v, const int ctrl) {
    int moved;
    switch (ctrl) {
        case 0x111: moved = __builtin_amdgcn_update_dpp(0, __float_as_int(v), 0x111, 0xf, 0xf, true); break;
        case 0x112: moved = __builtin_amdgcn_update_dpp(0, __float_as_int(v), 0x112, 0xf, 0xf, true); break;
        case 0x114: moved = __builtin_amdgcn_update_dpp(0, __float_as_int(v), 0x114, 0xf, 0xf, true); break;
        case 0x118: moved = __builtin_amdgcn_update_dpp(0, __float_as_int(v), 0x118, 0xf, 0xf, true); break;
        case 0x142: moved = __builtin_amdgcn_update_dpp(0, __float_as_int(v), 0x142, 0xf, 0xf, true); break;
        default:    moved = __builtin_amdgcn_update_dpp(0, __float_as_int(v), 0x143, 0xf, 0xf, true); break;
    }
    return v + __int_as_float(moved);
}

// Full 64-lane sum; result valid in lane 63. 6 VALU ops, 0 DS ops.
__device__ __forceinline__ float wave_sum63(float v) {
    v = dpp_add(v, 0x111);   // row_shr:1
    v = dpp_add(v, 0x112);   // row_shr:2
    v = dpp_add(v, 0x114);   // row_shr:4
    v = dpp_add(v, 0x118);   // row_shr:8  -> lane15/31/47/63 hold row sums
    v = dpp_add(v, 0x142);   // row_bcast15 -> lane31/63 hold half sums
    v = dpp_add(v, 0x143);   // row_bcast31 -> lane63 holds full sum
    return v;
}

// ---------------- Kernel 1: streaming pass over features ----------------
// BYTE-IDENTICAL to the round-2 (89 us) version. Do not touch without A/B.
__global__ __launch_bounds__(BLOCK) void loss_main(
    const float* __restrict__ feat, const int* __restrict__ labels,
    const float* __restrict__ center, float* __restrict__ partials,
    int nrows, int nblocks)
{
    __shared__ __align__(16) float s_center[CLS * D];   // 10 KiB
    __shared__ float s_cnorm[CLS];
    __shared__ float s_acc[NWAVE][2 * D];               // 8 KiB
    __shared__ float s_scal[NWAVE][3];

    for (int i = threadIdx.x; i < CLS * D; i += BLOCK) s_center[i] = center[i];
    __syncthreads();
    if (threadIdx.x < CLS) {
        float s = 0.f;
        #pragma unroll 8
        for (int d = 0; d < D; ++d) {
            float v = s_center[threadIdx.x * D + d];
            s = fmaf(v, v, s);
        }
        s_cnorm[threadIdx.x] = s;
    }
    __syncthreads();

    const int wave = threadIdx.x >> 6;
    const int lane = threadIdx.x & 63;
    const int gw = blockIdx.x * NWAVE + wave;
    const int nw = nblocks * NWAVE;

    float intra = 0.f, cnt8 = 0.f, cnt9 = 0.f;
    float a8x = 0.f, a8y = 0.f, a8z = 0.f, a8w = 0.f;
    float a9x = 0.f, a9y = 0.f, a9z = 0.f, a9w = 0.f;

    int r = gw;
    bool valid = r < nrows;
    int l = 0;
    float4 f = make_float4(0.f, 0.f, 0.f, 0.f);
    if (valid) {
        l = labels[r];
        f = *(const float4*)(feat + (size_t)r * D + (lane << 2));
    }

    while (valid) {
        const int rn = r + nw;
        const bool vn = rn < nrows;
        int ln = 0;
        float4 fn = make_float4(0.f, 0.f, 0.f, 0.f);
        if (vn) {
            ln = labels[rn];
            fn = *(const float4*)(feat + (size_t)rn * D + (lane << 2));
        }

        const float4 c = *(const float4*)(s_center + l * D + (lane << 2));
        // val = sum f*(f - 2c) = ||f||^2 - 2 f.c  (single reduced scalar)
        float tx = fmaf(-2.f, c.x, f.x);
        float ty = fmaf(-2.f, c.y, f.y);
        float tz = fmaf(-2.f, c.z, f.z);
        float tw = fmaf(-2.f, c.w, f.w);
        float val = f.x * tx;
        val = fmaf(f.y, ty, val);
        val = fmaf(f.z, tz, val);
        val = fmaf(f.w, tw, val);

        const float s = wave_sum63(val);
        if (lane == 63) {
            float d2 = fmaxf(s + s_cnorm[l], 0.f);
            float own = fminf(fmaxf(sqrtf(d2), 1e-16f), 1e16f);
            intra += own;
            cnt8 += (l == CLS - 2) ? 1.f : 0.f;
            cnt9 += (l == CLS - 1) ? 1.f : 0.f;
        }
        if (l == CLS - 2) { a8x += f.x; a8y += f.y; a8z += f.z; a8w += f.w; }
        if (l == CLS - 1) { a9x += f.x; a9y += f.y; a9z += f.z; a9w += f.w; }

        r = rn; l = ln; f = fn; valid = vn;
    }

    const int e = lane << 2;
    s_acc[wave][e + 0] = a8x;
    s_acc[wave][e + 1] = a8y;
    s_acc[wave][e + 2] = a8z;
    s_acc[wave][e + 3] = a8w;
    s_acc[wave][D + e + 0] = a9x;
    s_acc[wave][D + e + 1] = a9y;
    s_acc[wave][D + e + 2] = a9z;
    s_acc[wave][D + e + 3] = a9w;
    if (lane == 63) {
        s_scal[wave][0] = cnt8;
        s_scal[wave][1] = cnt9;
        s_scal[wave][2] = intra;
    }
    __syncthreads();

    float* po = partials + (size_t)blockIdx.x * PSTRIDE;
    for (int i = threadIdx.x; i < 2 * D; i += BLOCK)
        po[i] = s_acc[0][i] + s_acc[1][i] + s_acc[2][i] + s_acc[3][i];
    if (threadIdx.x < 3)
        po[2 * D + threadIdx.x] = s_scal[0][threadIdx.x] + s_scal[1][threadIdx.x]
                                + s_scal[2][threadIdx.x] + s_scal[3][threadIdx.x];
}

// ------- Kernel 2 (fused): tree reduce + last-block final combine -------
__global__ __launch_bounds__(BLOCK) void loss_tail(
    const float* __restrict__ partials, float* __restrict__ partials2,
    const float* __restrict__ center, float* __restrict__ out,
    unsigned* __restrict__ counter, int nblocks, int nrows)
{
    const int t = threadIdx.x;
    __shared__ bool is_last;

    // ---- stage 1: this block reduces its strided slice of partials ----
    float s0 = 0.f, s1 = 0.f, sc = 0.f;
    for (int r = blockIdx.x; r < nblocks; r += gridDim.x) {
        const float* p = partials + (size_t)r * PSTRIDE;
        s0 += p[t];
        s1 += p[D + t];
        if (t < 3) sc += p[2 * D + t];
    }
    float* o = partials2 + (size_t)blockIdx.x * PSTRIDE;
    o[t] = s0;
    o[D + t] = s1;
    if (t < 3) o[2 * D + t] = sc;

    // center passthrough (independent work, done in parallel by block 0)
    if (blockIdx.x == 0)
        for (int i = t; i < CLS * D; i += BLOCK) out[2 + i] = center[i];

    // ---- release: make stores device-visible, then count this block done ----
    __threadfence();
    __syncthreads();
    if (t == 0) {
        const unsigned old = atomicAdd(counter, 1u);
        is_last = (old == gridDim.x - 1);
    }
    __syncthreads();
    if (!is_last) return;
    __threadfence();  // acquire: see all other blocks' partials2 stores

    // ---- final combine (one block, fixed read order -> bit-deterministic) ----
    const int nred = gridDim.x;
    double s8 = 0.0, s9 = 0.0;
    for (int r = 0; r < nred; ++r) {
        const float* p = partials2 + (size_t)r * PSTRIDE;
        s8 += (double)p[t];
        s9 += (double)p[D + t];
    }
    __shared__ double sh[3];
    if (t < 3) {
        double s = 0.0;
        for (int r = 0; r < nred; ++r)
            s += (double)partials2[(size_t)r * PSTRIDE + 2 * D + t];
        sh[t] = s;
    }
    __shared__ double ssq[BLOCK];
    __syncthreads();

    const double cnt8 = fmax(sh[0], 1.0);
    const double cnt9 = fmax(sh[1], 1.0);
    const double c8 = ((double)center[(CLS - 2) * D + t] + s8) / cnt8;
    const double c9 = ((double)center[(CLS - 1) * D + t] + s9) / cnt9;
    const double diff = c8 - c9;
    ssq[t] = diff * diff;
    __syncthreads();

    for (int s = BLOCK / 2; s > 0; s >>= 1) {
        if (t < s) ssq[t] += ssq[t + s];
        __syncthreads();
    }

    if (t == 0) {
        const double last = sqrt(fmax(ssq[0], 0.0));
        const double denom = fmin(fmax(2.0 * last, 1e-16), 1e16);
        out[0] = (float)(sh[2] / (double)nrows);
        out[1] = (float)(1.0 / denom);
    }
}

extern "C" void kernel_launch(void* const* d_in, const int* in_sizes, int n_in,
                              void* d_out, int out_size, void* d_ws, size_t ws_size,
                              hipStream_t stream) {
    const float* feat   = (const float*)d_in[0];
    const int*   labels = (const int*)d_in[1];
    const float* center = (const float*)d_in[2];
    float* out = (float*)d_out;

    const int nrows = in_sizes[0] / D;

    int nblocks = MAIN_BLOCKS;
    while (nblocks > 64 &&
           ((size_t)nblocks + RED_BLOCKS + 1) * PSTRIDE * sizeof(float) > ws_size)
        nblocks >>= 1;

    float* partials  = (float*)d_ws;
    float* partials2 = partials + (size_t)nblocks * PSTRIDE;
    unsigned* counter = (unsigned*)(partials2 + (size_t)RED_BLOCKS * PSTRIDE);

    // zero the done-counter every call (ws is poisoned once, never re-poisoned)
    hipMemsetAsync(counter, 0, sizeof(unsigned), stream);

    loss_main<<<nblocks, BLOCK, 0, stream>>>(feat, labels, center, partials, nrows, nblocks);
    loss_tail<<<RED_BLOCKS, BLOCK, 0, stream>>>(partials, partials2, center, out,
                                                counter, nblocks, nrows);
}

// Round 6
// 88.788 us; speedup vs baseline: 1.4991x; 1.0842x over previous
//
#include <hip/hip_runtime.h>
#include <math.h>

#define D 256
#define CLS 10
#define BLOCK 256
#define NWAVE 4            // 256 threads / 64 lanes
#define PSTRIDE 516        // 512 class-sum floats + cnt8 + cnt9 + intra (+1 pad)
#define MAIN_BLOCKS 2048
#define RED_BLOCKS 64

// v += dpp_move(v, ctrl); invalid source lanes contribute 0 (bound_ctrl=1).
// Pure VALU — no LDS pipe traffic, unlike __shfl_xor (ds_bpermute).
__device__ __forceinline__ float dpp_add(float v, const int ctrl) {
    int moved;
    switch (ctrl) {
        case 0x111: moved = __builtin_amdgcn_update_dpp(0, __float_as_int(v), 0x111, 0xf, 0xf, true); break;
        case 0x112: moved = __builtin_amdgcn_update_dpp(0, __float_as_int(v), 0x112, 0xf, 0xf, true); break;
        case 0x114: moved = __builtin_amdgcn_update_dpp(0, __float_as_int(v), 0x114, 0xf, 0xf, true); break;
        case 0x118: moved = __builtin_amdgcn_update_dpp(0, __float_as_int(v), 0x118, 0xf, 0xf, true); break;
        case 0x142: moved = __builtin_amdgcn_update_dpp(0, __float_as_int(v), 0x142, 0xf, 0xf, true); break;
        default:    moved = __builtin_amdgcn_update_dpp(0, __float_as_int(v), 0x143, 0xf, 0xf, true); break;
    }
    return v + __int_as_float(moved);
}

// Full 64-lane sum; result valid in lane 63. 6 VALU ops, 0 DS ops.
__device__ __forceinline__ float wave_sum63(float v) {
    v = dpp_add(v, 0x111);   // row_shr:1
    v = dpp_add(v, 0x112);   // row_shr:2
    v = dpp_add(v, 0x114);   // row_shr:4
    v = dpp_add(v, 0x118);   // row_shr:8  -> lane15/31/47/63 hold row sums
    v = dpp_add(v, 0x142);   // row_bcast15 -> lane31/63 hold half sums
    v = dpp_add(v, 0x143);   // row_bcast31 -> lane63 holds full sum
    return v;
}

// The R2 (89us) per-row body, verbatim, as a macro so the depth-2 rotation
// duplicates it textually (no lambda, no call overhead, no asm).
#define PROCESS(LBL, F)                                                         \
    {                                                                           \
        const float4 c = *(const float4*)(s_center + (LBL) * D + (lane << 2));  \
        float tx = fmaf(-2.f, c.x, (F).x);                                      \
        float ty = fmaf(-2.f, c.y, (F).y);                                      \
        float tz = fmaf(-2.f, c.z, (F).z);                                      \
        float tw = fmaf(-2.f, c.w, (F).w);                                      \
        float val = (F).x * tx;                                                 \
        val = fmaf((F).y, ty, val);                                             \
        val = fmaf((F).z, tz, val);                                             \
        val = fmaf((F).w, tw, val);                                             \
        const float s = wave_sum63(val);                                        \
        if (lane == 63) {                                                       \
            float d2 = fmaxf(s + s_cnorm[(LBL)], 0.f);                          \
            float own = fminf(fmaxf(sqrtf(d2), 1e-16f), 1e16f);                 \
            intra += own;                                                       \
            cnt8 += ((LBL) == CLS - 2) ? 1.f : 0.f;                             \
            cnt9 += ((LBL) == CLS - 1) ? 1.f : 0.f;                             \
        }                                                                       \
        if ((LBL) == CLS - 2) { a8x += (F).x; a8y += (F).y; a8z += (F).z; a8w += (F).w; } \
        if ((LBL) == CLS - 1) { a9x += (F).x; a9y += (F).y; a9z += (F).z; a9w += (F).w; } \
    }

// ---------------- Kernel 1: streaming pass over features ----------------
// R2 body + ONLY change: depth-2 prefetch rotation (2 KiB/wave in flight).
__global__ __launch_bounds__(BLOCK) void loss_main(
    const float* __restrict__ feat, const int* __restrict__ labels,
    const float* __restrict__ center, float* __restrict__ partials,
    int nrows, int nblocks)
{
    __shared__ __align__(16) float s_center[CLS * D];   // 10 KiB
    __shared__ float s_cnorm[CLS];
    __shared__ float s_acc[NWAVE][2 * D];               // 8 KiB
    __shared__ float s_scal[NWAVE][3];

    for (int i = threadIdx.x; i < CLS * D; i += BLOCK) s_center[i] = center[i];
    __syncthreads();
    if (threadIdx.x < CLS) {
        float s = 0.f;
        #pragma unroll 8
        for (int d = 0; d < D; ++d) {
            float v = s_center[threadIdx.x * D + d];
            s = fmaf(v, v, s);
        }
        s_cnorm[threadIdx.x] = s;
    }
    __syncthreads();

    const int wave = threadIdx.x >> 6;
    const int lane = threadIdx.x & 63;
    const int gw = blockIdx.x * NWAVE + wave;
    const int nw = nblocks * NWAVE;

    float intra = 0.f, cnt8 = 0.f, cnt9 = 0.f;
    float a8x = 0.f, a8y = 0.f, a8z = 0.f, a8w = 0.f;
    float a9x = 0.f, a9y = 0.f, a9z = 0.f, a9w = 0.f;

    // depth-2 rotation: rows r, r+nw in flight; steady-state body unconditional
    int r = gw;
    const bool v0 = r < nrows;
    const bool v1 = r + nw < nrows;
    int l0 = 0, l1 = 0;
    float4 f0 = make_float4(0.f, 0.f, 0.f, 0.f), f1 = f0;
    if (v0) {
        l0 = labels[r];
        f0 = *(const float4*)(feat + (size_t)r * D + (lane << 2));
    }
    if (v1) {
        l1 = labels[r + nw];
        f1 = *(const float4*)(feat + ((size_t)r + nw) * D + (lane << 2));
    }

    while (r + 2 * nw < nrows) {
        const int l2 = labels[r + 2 * nw];
        const float4 f2 = *(const float4*)(feat + ((size_t)r + 2 * nw) * D + (lane << 2));

        PROCESS(l0, f0);

        l0 = l1; f0 = f1;
        l1 = l2; f1 = f2;
        r += nw;
    }
    if (v0) PROCESS(l0, f0);
    if (v1) PROCESS(l1, f1);

    const int e = lane << 2;
    s_acc[wave][e + 0] = a8x;
    s_acc[wave][e + 1] = a8y;
    s_acc[wave][e + 2] = a8z;
    s_acc[wave][e + 3] = a8w;
    s_acc[wave][D + e + 0] = a9x;
    s_acc[wave][D + e + 1] = a9y;
    s_acc[wave][D + e + 2] = a9z;
    s_acc[wave][D + e + 3] = a9w;
    if (lane == 63) {
        s_scal[wave][0] = cnt8;
        s_scal[wave][1] = cnt9;
        s_scal[wave][2] = intra;
    }
    __syncthreads();

    float* po = partials + (size_t)blockIdx.x * PSTRIDE;
    for (int i = threadIdx.x; i < 2 * D; i += BLOCK)
        po[i] = s_acc[0][i] + s_acc[1][i] + s_acc[2][i] + s_acc[3][i];
    if (threadIdx.x < 3)
        po[2 * D + threadIdx.x] = s_scal[0][threadIdx.x] + s_scal[1][threadIdx.x]
                                + s_scal[2][threadIdx.x] + s_scal[3][threadIdx.x];
}

// ---------------- Kernel 2: deterministic tree reduce of block partials ----------------
__global__ __launch_bounds__(BLOCK) void loss_reduce(
    const float* __restrict__ partials, float* __restrict__ out2, int nblocks)
{
    const int t = threadIdx.x;
    float s0 = 0.f, s1 = 0.f, sc = 0.f;
    for (int r = blockIdx.x; r < nblocks; r += gridDim.x) {
        const float* p = partials + (size_t)r * PSTRIDE;
        s0 += p[t];
        s1 += p[D + t];
        if (t < 3) sc += p[2 * D + t];
    }
    float* o = out2 + (size_t)blockIdx.x * PSTRIDE;
    o[t] = s0;
    o[D + t] = s1;
    if (t < 3) o[2 * D + t] = sc;
}

// ---------------- Kernel 3: final combine (fp64) + center copy ----------------
__global__ __launch_bounds__(BLOCK) void loss_final(
    const float* __restrict__ partials2, const float* __restrict__ center,
    float* __restrict__ out, int nred, int nrows)
{
    const int t = threadIdx.x;
    double s8 = 0.0, s9 = 0.0;
    for (int r = 0; r < nred; ++r) {
        const float* p = partials2 + (size_t)r * PSTRIDE;
        s8 += (double)p[t];
        s9 += (double)p[D + t];
    }
    __shared__ double sh[3];
    if (t < 3) {
        double s = 0.0;
        for (int r = 0; r < nred; ++r)
            s += (double)partials2[(size_t)r * PSTRIDE + 2 * D + t];
        sh[t] = s;
    }
    __shared__ double ssq[BLOCK];
    __syncthreads();

    const double cnt8 = fmax(sh[0], 1.0);
    const double cnt9 = fmax(sh[1], 1.0);
    const double c8 = ((double)center[(CLS - 2) * D + t] + s8) / cnt8;
    const double c9 = ((double)center[(CLS - 1) * D + t] + s9) / cnt9;
    const double diff = c8 - c9;
    ssq[t] = diff * diff;
    __syncthreads();

    for (int s = BLOCK / 2; s > 0; s >>= 1) {
        if (t < s) ssq[t] += ssq[t + s];
        __syncthreads();
    }

    if (t == 0) {
        const double last = sqrt(fmax(ssq[0], 0.0));
        const double denom = fmin(fmax(2.0 * last, 1e-16), 1e16);
        out[0] = (float)(sh[2] / (double)nrows);
        out[1] = (float)(1.0 / denom);
    }
    for (int i = t; i < CLS * D; i += BLOCK) out[2 + i] = center[i];
}

extern "C" void kernel_launch(void* const* d_in, const int* in_sizes, int n_in,
                              void* d_out, int out_size, void* d_ws, size_t ws_size,
                              hipStream_t stream) {
    const float* feat   = (const float*)d_in[0];
    const int*   labels = (const int*)d_in[1];
    const float* center = (const float*)d_in[2];
    float* out = (float*)d_out;

    const int nrows = in_sizes[0] / D;

    int nblocks = MAIN_BLOCKS;
    while (nblocks > 64 &&
           ((size_t)nblocks + RED_BLOCKS) * PSTRIDE * sizeof(float) > ws_size)
        nblocks >>= 1;

    float* partials  = (float*)d_ws;
    float* partials2 = partials + (size_t)nblocks * PSTRIDE;

    loss_main<<<nblocks, BLOCK, 0, stream>>>(feat, labels, center, partials, nrows, nblocks);
    loss_reduce<<<RED_BLOCKS, BLOCK, 0, stream>>>(partials, partials2, nblocks);
    loss_final<<<1, BLOCK, 0, stream>>>(partials2, center, out, RED_BLOCKS, nrows);
}